// Round 4
// baseline (202.658 us; speedup 1.0000x reference)
//
#include <hip/hip_runtime.h>
#include <hip/hip_bf16.h>

#define N_NODES 100000
#define N_EDGES 1250000
#define D_FEAT  64
#define E4      (N_EDGES / 4)                                      // 312500 exactly

#define SCAN_BLOCK 256
#define N_SCAN_BLOCKS ((N_NODES + SCAN_BLOCK - 1) / SCAN_BLOCK)    // 391
#define SCAN2_THREADS 512                                          // >= N_SCAN_BLOCKS

// Phase 1: histogram + per-edge rank, 4 edges/thread (int4 I/O, 4 atomics in flight)
__global__ __launch_bounds__(256) void histo_rank4(
    const int* __restrict__ dst, int* __restrict__ count, int* __restrict__ rank)
{
    int e4 = blockIdx.x * blockDim.x + threadIdx.x;
    if (e4 >= E4) return;
    int4 d = ((const int4*)dst)[e4];
    int4 r;
    r.x = atomicAdd(&count[d.x], 1);
    r.y = atomicAdd(&count[d.y], 1);
    r.z = atomicAdd(&count[d.z], 1);
    r.w = atomicAdd(&count[d.w], 1);
    ((int4*)rank)[e4] = r;
}

// Phase 2a: per-block local exclusive scan; block totals out
__global__ __launch_bounds__(SCAN_BLOCK) void scan_local(
    const int* __restrict__ count, int* __restrict__ offsets,
    int* __restrict__ blockSums)
{
    __shared__ int s[SCAN_BLOCK];
    const int t = threadIdx.x;
    const int idx = blockIdx.x * SCAN_BLOCK + t;
    const int my = (idx < N_NODES) ? count[idx] : 0;
    s[t] = my;
    __syncthreads();
    for (int off = 1; off < SCAN_BLOCK; off <<= 1) {
        int v = (t >= off) ? s[t - off] : 0;
        __syncthreads();
        s[t] += v;
        __syncthreads();
    }
    if (idx < N_NODES) offsets[idx] = s[t] - my;      // block-local exclusive
    if (t == SCAN_BLOCK - 1) blockSums[blockIdx.x] = s[t];
}

// Phase 2b: exclusive scan of the 391 block sums (single small block)
__global__ __launch_bounds__(SCAN2_THREADS) void scan_blocks(
    const int* __restrict__ blockSums, int* __restrict__ blockBase)
{
    __shared__ int s[SCAN2_THREADS];
    const int t = threadIdx.x;
    const int my = (t < N_SCAN_BLOCKS) ? blockSums[t] : 0;
    s[t] = my;
    __syncthreads();
    for (int off = 1; off < SCAN2_THREADS; off <<= 1) {
        int v = (t >= off) ? s[t - off] : 0;
        __syncthreads();
        s[t] += v;
        __syncthreads();
    }
    if (t < N_SCAN_BLOCKS) blockBase[t] = s[t] - my;  // exclusive base per scan block
}

// Phase 3: counting-sort scatter of src indices by dst, 4 edges/thread.
// True offset = offsets[d] + blockBase[d>>8] (blockBase is 1.5KB, L1-resident).
__global__ __launch_bounds__(256) void scatter_src4(
    const int* __restrict__ src, const int* __restrict__ dst,
    const int* __restrict__ rank, const int* __restrict__ offsets,
    const int* __restrict__ blockBase, int* __restrict__ sorted)
{
    int e4 = blockIdx.x * blockDim.x + threadIdx.x;
    if (e4 >= E4) return;
    int4 d = ((const int4*)dst)[e4];
    int4 r = ((const int4*)rank)[e4];
    int4 s = ((const int4*)src)[e4];
    sorted[offsets[d.x] + blockBase[d.x >> 8] + r.x] = s.x;
    sorted[offsets[d.y] + blockBase[d.y >> 8] + r.y] = s.y;
    sorted[offsets[d.z] + blockBase[d.z >> 8] + r.z] = s.z;
    sorted[offsets[d.w] + blockBase[d.w >> 8] + r.w] = s.w;
}

// Phase 4: one wave per node; 4 edges in flight (lane = edge-subgroup*16 + quad).
// Cross-group reduce via shfl_xor(16), shfl_xor(32); lanes 0-15 store the row.
__global__ __launch_bounds__(256) void gather_sum_wave(
    const float* __restrict__ x, const int* __restrict__ sorted,
    const int* __restrict__ offsets, const int* __restrict__ blockBase,
    float* __restrict__ out)
{
    const int lane = threadIdx.x & 63;
    const int node = blockIdx.x * 4 + (threadIdx.x >> 6);
    if (node >= N_NODES) return;
    const int equad = lane >> 4;   // which of the 4 concurrent edges
    const int quad  = lane & 15;   // which float4 of the 64-feat row

    const int start = offsets[node] + blockBase[node >> 8];
    const int end = (node + 1 < N_NODES)
        ? offsets[node + 1] + blockBase[(node + 1) >> 8]
        : N_EDGES;

    float4 acc = {0.f, 0.f, 0.f, 0.f};
    const float4* __restrict__ x4 = (const float4*)x;  // row = 16 float4s

    for (int i = start + equad; i < end; i += 4) {
        int s = sorted[i];
        float4 v = x4[(size_t)s * 16 + quad];
        acc.x += v.x; acc.y += v.y; acc.z += v.z; acc.w += v.w;
    }

    // reduce the 4 edge-subgroups: lane l <-> l^16, then l^32
    acc.x += __shfl_xor(acc.x, 16, 64); acc.y += __shfl_xor(acc.y, 16, 64);
    acc.z += __shfl_xor(acc.z, 16, 64); acc.w += __shfl_xor(acc.w, 16, 64);
    acc.x += __shfl_xor(acc.x, 32, 64); acc.y += __shfl_xor(acc.y, 32, 64);
    acc.z += __shfl_xor(acc.z, 32, 64); acc.w += __shfl_xor(acc.w, 32, 64);

    if (lane < 16) ((float4*)out)[(size_t)node * 16 + quad] = acc;
}

extern "C" void kernel_launch(void* const* d_in, const int* in_sizes, int n_in,
                              void* d_out, int out_size, void* d_ws, size_t ws_size,
                              hipStream_t stream) {
    const float* x = (const float*)d_in[0];
    const int* edge_index = (const int*)d_in[1];    // [2, N_EDGES] flat int32
    const int* src = edge_index;
    const int* dst = edge_index + N_EDGES;
    float* out = (float*)d_out;

    // Workspace (ints), 16B-alignment-friendly order:
    // rank[E] | sorted[E] | count[N] | offsets[N+1] | blockSums | blockBase
    int* rank      = (int*)d_ws;
    int* sorted    = rank + N_EDGES;
    int* count     = sorted + N_EDGES;
    int* offsets   = count + N_NODES;
    int* blockSums = offsets + (N_NODES + 1);
    int* blockBase = blockSums + N_SCAN_BLOCKS;

    hipMemsetAsync(count, 0, (size_t)N_NODES * sizeof(int), stream);

    const int eb = 256;
    const int eg4 = (E4 + eb - 1) / eb;
    histo_rank4<<<eg4, eb, 0, stream>>>(dst, count, rank);

    scan_local<<<N_SCAN_BLOCKS, SCAN_BLOCK, 0, stream>>>(count, offsets, blockSums);
    scan_blocks<<<1, SCAN2_THREADS, 0, stream>>>(blockSums, blockBase);

    scatter_src4<<<eg4, eb, 0, stream>>>(src, dst, rank, offsets, blockBase, sorted);

    gather_sum_wave<<<(N_NODES + 3) / 4, 256, 0, stream>>>(
        x, sorted, offsets, blockBase, out);
}